// Round 10
// baseline (456.568 us; speedup 1.0000x reference)
//
#include <hip/hip_runtime.h>
#include <hip/hip_bf16.h>
#include <hip/hip_cooperative_groups.h>
#include <math.h>

namespace cg = cooperative_groups;

#define D 64

typedef __attribute__((ext_vector_type(8))) short bf16x8;
typedef __attribute__((ext_vector_type(8))) _Float16 f16x8;
typedef __attribute__((ext_vector_type(8))) unsigned short u16x8;
typedef __attribute__((ext_vector_type(4))) float f32x4;
typedef unsigned short u16;

__device__ __forceinline__ float gelu_erf(float x) {
    return 0.5f * x * (1.0f + erff(x * 0.70710678118654752f));
}
__device__ __forceinline__ float gelu_tanh(float x) {
    float u = x * fmaf(x * x, 0.035677408136f, 0.7978845608028654f);
    float e = __expf(2.0f * u);
    float th = 1.0f - 2.0f / (e + 1.0f);
    return 0.5f * x * (1.0f + th);
}
__device__ __forceinline__ u16 f2bf(float v) {
    __hip_bfloat16 h = __float2bfloat16(v);
    return *(u16*)&h;
}
__device__ __forceinline__ float bf2f(u16 v) {
    return __uint_as_float(((unsigned int)v) << 16);
}
__device__ __forceinline__ u16 f2h(float v) {
    _Float16 h = (_Float16)v;
    return __builtin_bit_cast(u16, h);
}
__device__ __forceinline__ void atomic_pk_add_f16(u16* addr, float lo, float hi) {
    unsigned int p = (unsigned int)f2h(lo) | ((unsigned int)f2h(hi) << 16);
    asm volatile("global_atomic_pk_add_f16 %0, %1, off sc1" :: "v"(addr), "v"(p));
}
// pos p holds dim pi(p) = (p&3)*16 + (p>>2)
__device__ __forceinline__ int pi_perm(int p) { return ((p & 3) << 4) | (p >> 2); }

// B-fragment from row-major W[n][k] (ld=64): k consecutive -> vector loads
__device__ __forceinline__ bf16x8 fragT64(const float* __restrict__ W, int nt, int kk,
                                          int c, int quad) {
    const float* p = W + (nt * 16 + c) * 64 + kk * 32 + quad * 8;
    f32x4 v0 = *(const f32x4*)p;
    f32x4 v1 = *(const f32x4*)(p + 4);
    bf16x8 r;
    #pragma unroll
    for (int j = 0; j < 4; ++j) { r[j] = (short)f2bf(v0[j]); r[4 + j] = (short)f2bf(v1[j]); }
    return r;
}
// B-fragment from W[k][n] (Wks/Wkd layout): stride-64 scalar loads
__device__ __forceinline__ bf16x8 fragK64(const float* __restrict__ W, int nt, int kk,
                                          int c, int quad) {
    int n = nt * 16 + c, k0 = kk * 32 + quad * 8;
    bf16x8 r;
    #pragma unroll
    for (int j = 0; j < 8; ++j) r[j] = (short)f2bf(W[(k0 + j) * 64 + n]);
    return r;
}

// ---- K1 (fat): [0,GQ) qgemm (raw-weight frags) | [GQ,GQ+6) pack WtB/WvsB/WvdB | rest hist
__global__ __launch_bounds__(256) void k1_fused(
    const float* __restrict__ x, const float* __restrict__ gamma, const float* __restrict__ beta,
    const float* __restrict__ Wt, const float* __restrict__ Wq,
    const float* __restrict__ Wks, const float* __restrict__ Wkd,
    const float* __restrict__ Wvs, const float* __restrict__ Wvd,
    const float* __restrict__ bq, const float* __restrict__ bks, const float* __restrict__ bkd,
    u16* __restrict__ WtB, u16* __restrict__ WvsB, u16* __restrict__ WvdB,
    u16* __restrict__ xnb, u16* __restrict__ qk2, float* __restrict__ bq2,
    const int* __restrict__ ei, const float* __restrict__ esame, int* __restrict__ cnt,
    int N, int E, int GQ)
{
    __shared__ u16 qtile[4][16 * 64];
    __shared__ u16 stile[4][32 * 64];

    if (blockIdx.x >= GQ + 6) {
        // ---------- histogram ----------
        int gid = (blockIdx.x - GQ - 6) * 256 + threadIdx.x;
        int stride = (gridDim.x - GQ - 6) * 256;
        for (int e = gid; e < E; e += stride) {
            int key = 2 * ei[E + e] + (esame[e] > 0.5f ? 0 : 1);
            atomicAdd(&cnt[key], 1);
        }
        return;
    }
    if (blockIdx.x >= GQ) {
        // ---------- pack WtB / WvsB / WvdB ----------
        int task = (blockIdx.x - GQ) * 4 + (threadIdx.x >> 6);  // 0..23
        int lane = threadIdx.x & 63;
        int wsel = task >> 3, f = task & 7;
        int c = lane & 15, quad = lane >> 4;
        int nt = f >> 1, kk = f & 1;
        for (int j = 0; j < 8; ++j) {
            int n = nt * 16 + c, k = kk * 32 + quad * 8 + j;
            if (wsel == 0)      WtB[(f * 64 + lane) * 8 + j]  = f2bf(Wt[n * 65 + k]);
            else if (wsel == 1) WvsB[(f * 64 + lane) * 8 + j] = f2h(Wvs[n * 64 + pi_perm(k)]);
            else                WvdB[(f * 64 + lane) * 8 + j] = f2h(Wvd[n * 64 + pi_perm(k)]);
        }
        return;
    }

    // ---------- qgemm: fused LN + q-chain ----------
    const int lane = threadIdx.x & 63;
    const int c = lane & 15, quad = lane >> 4;
    const int w = threadIdx.x >> 6;
    const int wave = blockIdx.x * 4 + w;
    const int n0r = wave * 16;
    const bool active = n0r < N;
    const int n0 = active ? n0r : 0;
    const int rowA = (n0 + c < N) ? n0 + c : N - 1;

    // fused LayerNorm in A-fragment layout
    const float* xrow = x + (long)rowA * D;
    f32x4 xa = *(const f32x4*)(xrow + quad * 8);
    f32x4 xb = *(const f32x4*)(xrow + quad * 8 + 4);
    f32x4 xc = *(const f32x4*)(xrow + 32 + quad * 8);
    f32x4 xd = *(const f32x4*)(xrow + 32 + quad * 8 + 4);
    float s = 0.f, s2 = 0.f;
    #pragma unroll
    for (int j = 0; j < 4; ++j) {
        s += xa[j] + xb[j] + xc[j] + xd[j];
        s2 += xa[j] * xa[j] + xb[j] * xb[j] + xc[j] * xc[j] + xd[j] * xd[j];
    }
    s += __shfl_xor(s, 16);  s += __shfl_xor(s, 32);
    s2 += __shfl_xor(s2, 16); s2 += __shfl_xor(s2, 32);
    float mu = s * (1.0f / 64.0f);
    float var = s2 * (1.0f / 64.0f) - mu * mu;
    float rinv = rsqrtf(var + 1e-5f);
    f32x4 ga = *(const f32x4*)(gamma + quad * 8);
    f32x4 gb = *(const f32x4*)(gamma + quad * 8 + 4);
    f32x4 gc = *(const f32x4*)(gamma + 32 + quad * 8);
    f32x4 gd = *(const f32x4*)(gamma + 32 + quad * 8 + 4);
    f32x4 ba = *(const f32x4*)(beta + quad * 8);
    f32x4 bb = *(const f32x4*)(beta + quad * 8 + 4);
    f32x4 bc = *(const f32x4*)(beta + 32 + quad * 8);
    f32x4 bd = *(const f32x4*)(beta + 32 + quad * 8 + 4);
    bf16x8 a0, a1;
    #pragma unroll
    for (int j = 0; j < 4; ++j) {
        a0[j]     = (short)f2bf(fmaf((xa[j] - mu) * rinv, ga[j], ba[j]));
        a0[4 + j] = (short)f2bf(fmaf((xb[j] - mu) * rinv, gb[j], bb[j]));
        a1[j]     = (short)f2bf(fmaf((xc[j] - mu) * rinv, gc[j], bc[j]));
        a1[4 + j] = (short)f2bf(fmaf((xd[j] - mu) * rinv, gd[j], bd[j]));
    }
    *(bf16x8*)(xnb + (long)rowA * D + quad * 8) = a0;
    *(bf16x8*)(xnb + (long)rowA * D + 32 + quad * 8) = a1;

    float bqc[4], bksc[4], bkdc[4];
    #pragma unroll
    for (int t = 0; t < 4; ++t) {
        bqc[t] = bq[t * 16 + c]; bksc[t] = bks[t * 16 + c]; bkdc[t] = bkd[t * 16 + c];
    }

    // GEMM1: q (fragments built from raw Wq)
    f32x4 accq[4];
    #pragma unroll
    for (int t = 0; t < 4; ++t) {
        bf16x8 b0 = fragT64(Wq, t, 0, c, quad);
        bf16x8 b1 = fragT64(Wq, t, 1, c, quad);
        f32x4 z = {0.f, 0.f, 0.f, 0.f};
        z = __builtin_amdgcn_mfma_f32_16x16x32_bf16(a0, b0, z, 0, 0, 0);
        z = __builtin_amdgcn_mfma_f32_16x16x32_bf16(a1, b1, z, 0, 0, 0);
        accq[t] = z;
    }
    #pragma unroll
    for (int r = 0; r < 4; ++r) {
        float qv[4], ss = 0.f, sd = 0.f;
        #pragma unroll
        for (int t = 0; t < 4; ++t) {
            qv[t] = accq[t][r] + bqc[t];
            ss = fmaf(qv[t], bksc[t], ss);
            sd = fmaf(qv[t], bkdc[t], sd);
        }
        #pragma unroll
        for (int o = 1; o < 16; o <<= 1) { ss += __shfl_xor(ss, o); sd += __shfl_xor(sd, o); }
        int nrow = n0 + quad * 4 + r;
        if (active && c == 0 && nrow < N)
            *(float2*)(bq2 + 2 * nrow) = make_float2(ss, sd);
        #pragma unroll
        for (int t = 0; t < 4; ++t)
            qtile[w][(quad * 4 + r) * 64 + t * 16 + c] = f2bf(qv[t]);
    }
    __syncthreads();

    // GEMM2: qks/qkd -> stile rows (2m, 2m+1), pi-permuted positions
    const u16* qrow = &qtile[w][c * 64 + quad * 8];
    bf16x8 q0 = *(const bf16x8*)(qrow);
    bf16x8 q1 = *(const bf16x8*)(qrow + 32);
    #pragma unroll
    for (int t = 0; t < 4; ++t) {
        bf16x8 bs0 = fragK64(Wks, t, 0, c, quad);
        bf16x8 bs1 = fragK64(Wks, t, 1, c, quad);
        bf16x8 bd0 = fragK64(Wkd, t, 0, c, quad);
        bf16x8 bd1 = fragK64(Wkd, t, 1, c, quad);
        f32x4 zs = {0.f, 0.f, 0.f, 0.f}, zd = {0.f, 0.f, 0.f, 0.f};
        zs = __builtin_amdgcn_mfma_f32_16x16x32_bf16(q0, bs0, zs, 0, 0, 0);
        zs = __builtin_amdgcn_mfma_f32_16x16x32_bf16(q1, bs1, zs, 0, 0, 0);
        zd = __builtin_amdgcn_mfma_f32_16x16x32_bf16(q0, bd0, zd, 0, 0, 0);
        zd = __builtin_amdgcn_mfma_f32_16x16x32_bf16(q1, bd1, zd, 0, 0, 0);
        #pragma unroll
        for (int r = 0; r < 4; ++r) {
            int m = quad * 4 + r;
            stile[w][(2 * m + 0) * 64 + c * 4 + t] = f2bf(zs[r]);
            stile[w][(2 * m + 1) * 64 + c * 4 + t] = f2bf(zd[r]);
        }
    }
    __syncthreads();
    if (active) {
        int nrows = min(16, N - n0);
        const u16x8* sp = (const u16x8*)&stile[w][0];
        u16x8* dp = (u16x8*)(qk2 + (long)(2 * n0) * D);
        int cnt8 = nrows * 16;
        for (int j = lane; j < cnt8; j += 64) dp[j] = sp[j];
    }
}

// ---- K2 (cooperative): hierarchical scan (3 phases) + counting-sort scatter
__global__ __launch_bounds__(256) void sort_coop(
    const int* __restrict__ cnt, int* __restrict__ cursor, int* __restrict__ bsum,
    const int* __restrict__ ei, const float* __restrict__ et,
    const float* __restrict__ esame,
    int2* __restrict__ ev, int* __restrict__ keyv, int E, int M)
{
    cg::grid_group grid = cg::this_grid();
    __shared__ int shm[256];
    const int G = gridDim.x;
    const int b = blockIdx.x, t = threadIdx.x;
    const int chunkM = (M + G - 1) / G;
    const int perT = (chunkM + 255) / 256;     // elements per thread (contiguous)

    // phase A: block sums
    {
        int s = 0;
        int base = b * chunkM + t * perT;
        for (int j = 0; j < perT; ++j) {
            int idx = base + j;
            s += (j < perT && idx < M && (t * perT + j) < chunkM) ? cnt[idx] : 0;
        }
        #pragma unroll
        for (int o = 32; o; o >>= 1) s += __shfl_xor(s, o);
        if ((t & 63) == 0) shm[t >> 6] = s;
        __syncthreads();
        if (t == 0) bsum[b] = shm[0] + shm[1] + shm[2] + shm[3];
    }
    grid.sync();

    // phase B: block 0 exclusive-scans bsum[0..G) (2 per thread, G <= 512)
    if (b == 0) {
        int v0 = (2 * t < G) ? bsum[2 * t] : 0;
        int v1 = (2 * t + 1 < G) ? bsum[2 * t + 1] : 0;
        int ps = v0 + v1;
        shm[t] = ps;
        __syncthreads();
        for (int o = 1; o < 256; o <<= 1) {
            int u = (t >= o) ? shm[t - o] : 0;
            __syncthreads();
            shm[t] += u;
            __syncthreads();
        }
        int excl = t ? shm[t - 1] : 0;
        if (2 * t < G) bsum[2 * t] = excl;
        if (2 * t + 1 < G) bsum[2 * t + 1] = excl + v0;
    }
    grid.sync();

    // phase C: local exclusive scan + block offset -> cursor
    {
        int vals[8];
        int base = b * chunkM + t * perT;
        int tsum = 0;
        for (int j = 0; j < perT; ++j) {
            int idx = base + j;
            vals[j] = (idx < M && (t * perT + j) < chunkM) ? cnt[idx] : 0;
            tsum += vals[j];
        }
        int lane = t & 63, w = t >> 6;
        int inc = tsum;
        #pragma unroll
        for (int o = 1; o < 64; o <<= 1) {
            int u = __shfl_up(inc, o);
            if (lane >= o) inc += u;
        }
        __syncthreads();   // shm reuse safety
        if (lane == 63) shm[w] = inc;
        __syncthreads();
        int woff = 0;
        #pragma unroll
        for (int k = 0; k < 4; ++k) woff += (k < w) ? shm[k] : 0;
        int excl = woff + (inc - tsum) + bsum[b];
        for (int j = 0; j < perT; ++j) {
            int idx = base + j;
            if (idx < M && (t * perT + j) < chunkM) cursor[idx] = excl;
            excl += vals[j];
        }
    }
    grid.sync();

    // phase D: scatter
    {
        int gid = b * 256 + t, stride = G * 256;
        for (int e = gid; e < E; e += stride) {
            int key = 2 * ei[E + e] + (esame[e] > 0.5f ? 0 : 1);
            int pos = atomicAdd(&cursor[key], 1);
            ev[pos] = make_int2(ei[e], __float_as_int(et[e]));
            keyv[pos] = key;
        }
    }
}

// ---- K3: edge pass over key-sorted edges (run-aggregation in registers)
__global__ __launch_bounds__(256) void edge_pass(
    const int2* __restrict__ ev, const int* __restrict__ keyv,
    const u16* __restrict__ xnb, const u16* __restrict__ WtB,
    const float* __restrict__ Wt, const float* __restrict__ bt,
    const u16* __restrict__ qk2, const float* __restrict__ bq2,
    u16* __restrict__ A, float* __restrict__ den, int E, int chunk)
{
    const int lane = threadIdx.x & 63;
    const int c = lane & 15, quad = lane >> 4;
    const int wave = blockIdx.x * 4 + (threadIdx.x >> 6);
    const long base = (long)wave * chunk;
    if (base >= E) return;
    const long end = (base + chunk < (long)E) ? base + chunk : (long)E;
    const int qchunk = chunk >> 2;

    bf16x8 bfrag[8];
    #pragma unroll
    for (int f = 0; f < 8; ++f)
        bfrag[f] = *(const bf16x8*)(WtB + (f * 64 + lane) * 8);

    float btc[4], w64c[4], dva[4];
    #pragma unroll
    for (int t = 0; t < 4; ++t) {
        int dim = t * 16 + c;
        btc[t] = bt[dim];
        w64c[t] = Wt[dim * 65 + 64];
        dva[t] = 200.0f * expf(-9.210340371976184f * (float)(2 * (dim >> 1)) * (1.0f / 64.0f));
    }
    const float phoff = (c & 1) ? 1.5707963267948966f : 0.0f;

    int cur_key = -1;
    float racc0 = 0.f, racc1 = 0.f, racc2 = 0.f, racc3 = 0.f, rden = 0.f;
    ushort4 q4 = {0, 0, 0, 0};
    float bqv = 0.f;

    const long rowbase = base + (long)(c >> 2) * qchunk + (c & 3);

    for (int i = 0; i < qchunk; i += 4) {
        long eidx = rowbase + i;
        long ec = eidx < end ? eidx : end - 1;
        int2 evv = ev[ec];
        int keyL = keyv[ec];
        int srcL = evv.x;
        float tL = __int_as_float(evv.y);

        const u16* ar = xnb + (long)srcL * D + quad * 8;
        bf16x8 a0 = *(const bf16x8*)(ar);
        bf16x8 a1 = *(const bf16x8*)(ar + 32);

        f32x4 acc[4];
        #pragma unroll
        for (int t = 0; t < 4; ++t) {
            f32x4 z = {0.f, 0.f, 0.f, 0.f};
            z = __builtin_amdgcn_mfma_f32_16x16x32_bf16(a0, bfrag[t * 2 + 0], z, 0, 0, 0);
            z = __builtin_amdgcn_mfma_f32_16x16x32_bf16(a1, bfrag[t * 2 + 1], z, 0, 0, 0);
            acc[t] = z;
        }

        #pragma unroll
        for (int r = 0; r < 4; ++r) {
            int m = quad * 4 + r;
            int keym = __shfl(keyL, m);
            float tm = __shfl(tL, m);
            long eglob = base + (long)quad * qchunk + i + r;
            bool vm = eglob < end;

            float xtv[4];
            #pragma unroll
            for (int t = 0; t < 4; ++t) {
                float v = gelu_tanh(acc[t][r] + fmaf(tm, w64c[t], btc[t]));
                v += __sinf(fmaf(tm, dva[t], phoff));
                xtv[t] = v;
            }

            if (keym != cur_key) {
                if (cur_key >= 0) {
                    u16* ap = A + (long)cur_key * D + c * 4;
                    atomic_pk_add_f16(ap, racc0, racc1);
                    atomic_pk_add_f16(ap + 2, racc2, racc3);
                    if (c == 0) atomicAdd(&den[cur_key], rden);
                }
                cur_key = keym;
                q4 = *(const ushort4*)(qk2 + (long)keym * D + c * 4);
                bqv = bq2[keym];
                racc0 = racc1 = racc2 = racc3 = 0.f;
                rden = 0.f;
            }

            float p = xtv[0] * bf2f(q4.x);
            p = fmaf(xtv[1], bf2f(q4.y), p);
            p = fmaf(xtv[2], bf2f(q4.z), p);
            p = fmaf(xtv[3], bf2f(q4.w), p);
            #pragma unroll
            for (int o = 1; o < 16; o <<= 1) p += __shfl_xor(p, o);
            float ex = vm ? __expf((p + bqv) * 0.125f) : 0.0f;

            racc0 = fmaf(ex, xtv[0], racc0);
            racc1 = fmaf(ex, xtv[1], racc1);
            racc2 = fmaf(ex, xtv[2], racc2);
            racc3 = fmaf(ex, xtv[3], racc3);
            if (c == 0) rden += ex;
        }
    }

    if (cur_key >= 0) {
        u16* ap = A + (long)cur_key * D + c * 4;
        atomic_pk_add_f16(ap, racc0, racc1);
        atomic_pk_add_f16(ap + 2, racc2, racc3);
        if (c == 0) atomicAdd(&den[cur_key], rden);
    }
}

// ---- K4: node post (MFMA value-GEMM + output)
__global__ __launch_bounds__(256) void vgemm(
    const float* __restrict__ x, const u16* __restrict__ A, const float* __restrict__ den,
    const u16* __restrict__ WvsB, const u16* __restrict__ WvdB,
    const float* __restrict__ bvs, const float* __restrict__ bvd,
    float* __restrict__ out, int N)
{
    const int lane = threadIdx.x & 63;
    const int c = lane & 15, quad = lane >> 4;
    const int wave = blockIdx.x * 4 + (threadIdx.x >> 6);
    const int n0 = wave * 16;
    if (n0 >= N) return;
    const int rowA = (n0 + c < N) ? n0 + c : N - 1;

    float bvsc[4], bvdc[4];
    #pragma unroll
    for (int t = 0; t < 4; ++t) { bvsc[t] = bvs[t * 16 + c]; bvdc[t] = bvd[t * 16 + c]; }

    const u16* srow = A + (long)(2 * rowA) * D + quad * 8;
    const u16* drow = A + (long)(2 * rowA + 1) * D + quad * 8;
    f16x8 s0 = *(const f16x8*)(srow);
    f16x8 s1 = *(const f16x8*)(srow + 32);
    f16x8 d0 = *(const f16x8*)(drow);
    f16x8 d1 = *(const f16x8*)(drow + 32);

    f32x4 oacc[4];
    #pragma unroll
    for (int t = 0; t < 4; ++t) {
        f16x8 bs0 = *(const f16x8*)(WvsB + ((t * 2 + 0) * 64 + lane) * 8);
        f16x8 bs1 = *(const f16x8*)(WvsB + ((t * 2 + 1) * 64 + lane) * 8);
        f16x8 bd0 = *(const f16x8*)(WvdB + ((t * 2 + 0) * 64 + lane) * 8);
        f16x8 bd1 = *(const f16x8*)(WvdB + ((t * 2 + 1) * 64 + lane) * 8);
        f32x4 z = {0.f, 0.f, 0.f, 0.f};
        z = __builtin_amdgcn_mfma_f32_16x16x32_f16(s0, bs0, z, 0, 0, 0);
        z = __builtin_amdgcn_mfma_f32_16x16x32_f16(s1, bs1, z, 0, 0, 0);
        z = __builtin_amdgcn_mfma_f32_16x16x32_f16(d0, bd0, z, 0, 0, 0);
        z = __builtin_amdgcn_mfma_f32_16x16x32_f16(d1, bd1, z, 0, 0, 0);
        oacc[t] = z;
    }

    #pragma unroll
    for (int r = 0; r < 4; ++r) {
        int n = n0 + quad * 4 + r;
        if (n >= N) continue;
        float ds = den[2 * n], dd = den[2 * n + 1];
        float inv = 1.0f / (ds + dd + 1e-16f);
        float fs = ds * inv, fd = dd * inv;
        #pragma unroll
        for (int t = 0; t < 4; ++t) {
            long idx = (long)n * D + t * 16 + c;
            float o = fmaf(oacc[t][r], inv, fmaf(fs, bvsc[t], fd * bvdc[t]));
            out[idx] = x[idx] + gelu_erf(o);
        }
    }
}

extern "C" void kernel_launch(void* const* d_in, const int* in_sizes, int n_in,
                              void* d_out, int out_size, void* d_ws, size_t ws_size,
                              hipStream_t stream) {
    const float* x        = (const float*)d_in[0];
    const int*   ei       = (const int*)d_in[1];
    const float* et       = (const float*)d_in[2];
    const float* esame    = (const float*)d_in[4];
    const float* ln_gamma = (const float*)d_in[5];
    const float* ln_beta  = (const float*)d_in[6];
    const float* Wt  = (const float*)d_in[7];
    const float* bt  = (const float*)d_in[8];
    const float* Wq  = (const float*)d_in[9];
    const float* bq  = (const float*)d_in[10];
    const float* Wks = (const float*)d_in[11];
    const float* bks = (const float*)d_in[12];
    const float* Wkd = (const float*)d_in[13];
    const float* bkd = (const float*)d_in[14];
    const float* Wvs = (const float*)d_in[15];
    const float* bvs = (const float*)d_in[16];
    const float* Wvd = (const float*)d_in[17];
    const float* bvd = (const float*)d_in[18];
    float* out = (float*)d_out;

    const int N = in_sizes[0] / D;   // 50000
    const int E = in_sizes[2];       // 800000
    const int M = 2 * N;             // key space

    u16* A      = (u16*)d_ws;
    float* den  = (float*)(A + (long)M * D);
    int* cnt    = (int*)(den + M);
    int* cursor = cnt + M;
    float* bq2  = (float*)(cursor + M);
    int2* ev    = (int2*)(bq2 + M);
    int* keyv   = (int*)(ev + E);
    int* bsum   = keyv + E;                      // scan block sums (<=512)
    u16* xnb    = (u16*)(bsum + 512);
    u16* qk2    = xnb + (long)N * D;
    u16* WtB    = qk2 + (long)M * D;
    u16* WvsB   = WtB + 4096;
    u16* WvdB   = WvsB + 4096;

    // zero A + den + cnt in one shot (contiguous)
    hipMemsetAsync(A, 0, (size_t)M * D * 2 + (size_t)M * 4 * 2, stream);

    const int GQ = ((N + 15) / 16 + 3) / 4;      // qgemm blocks (782)
    const int GH = 488;                          // hist blocks
    k1_fused<<<GQ + 6 + GH, 256, 0, stream>>>(
        x, ln_gamma, ln_beta, Wt, Wq, Wks, Wkd, Wvs, Wvd, bq, bks, bkd,
        WtB, WvsB, WvdB, xnb, qk2, bq2, ei, esame, cnt, N, E, GQ);

    {
        int Ec = E, Mc = M;
        void* args[] = {(void*)&cnt, (void*)&cursor, (void*)&bsum,
                        (void*)&ei, (void*)&et, (void*)&esame,
                        (void*)&ev, (void*)&keyv, (void*)&Ec, (void*)&Mc};
        hipLaunchCooperativeKernel((const void*)sort_coop, dim3(512), dim3(256),
                                   args, 0, stream);
    }

    const int nwaves = 2048 * 4;
    const int chunk = ((E + nwaves * 16 - 1) / (nwaves * 16)) * 16;  // 112 @ E=800k
    edge_pass<<<2048, 256, 0, stream>>>(ev, keyv, xnb, WtB, Wt, bt,
                                        qk2, bq2, A, den, E, chunk);
    vgemm<<<GQ, 256, 0, stream>>>(x, A, den, WvsB, WvdB, bvs, bvd, out, N);
}

// Round 11
// 278.236 us; speedup vs baseline: 1.6409x; 1.6409x over previous
//
#include <hip/hip_runtime.h>
#include <hip/hip_bf16.h>
#include <math.h>

#define D 64

typedef __attribute__((ext_vector_type(8))) short bf16x8;
typedef __attribute__((ext_vector_type(8))) _Float16 f16x8;
typedef __attribute__((ext_vector_type(8))) unsigned short u16x8;
typedef __attribute__((ext_vector_type(4))) float f32x4;
typedef unsigned short u16;

__device__ __forceinline__ float gelu_erf(float x) {
    return 0.5f * x * (1.0f + erff(x * 0.70710678118654752f));
}
__device__ __forceinline__ float gelu_tanh(float x) {
    float u = x * fmaf(x * x, 0.035677408136f, 0.7978845608028654f);
    float e = __expf(2.0f * u);
    float th = 1.0f - 2.0f / (e + 1.0f);
    return 0.5f * x * (1.0f + th);
}
__device__ __forceinline__ u16 f2bf(float v) {
    __hip_bfloat16 h = __float2bfloat16(v);
    return *(u16*)&h;
}
__device__ __forceinline__ float bf2f(u16 v) {
    return __uint_as_float(((unsigned int)v) << 16);
}
__device__ __forceinline__ u16 f2h(float v) {
    _Float16 h = (_Float16)v;
    return __builtin_bit_cast(u16, h);
}
__device__ __forceinline__ void atomic_pk_add_f16(u16* addr, float lo, float hi) {
    unsigned int p = (unsigned int)f2h(lo) | ((unsigned int)f2h(hi) << 16);
    asm volatile("global_atomic_pk_add_f16 %0, %1, off sc1" :: "v"(addr), "v"(p));
}
// pos p holds dim pi(p) = (p&3)*16 + (p>>2)
__device__ __forceinline__ int pi_perm(int p) { return ((p & 3) << 4) | (p >> 2); }

// ---- K1: weight B-fragment packing (blocks 0..11) + key histogram (rest)
// key = 2*dst + (same ? 0 : 1)
__global__ __launch_bounds__(256) void prep_hist(
    const float* __restrict__ Wt, const float* __restrict__ Wq,
    const float* __restrict__ Wks, const float* __restrict__ Wkd,
    const float* __restrict__ Wvs, const float* __restrict__ Wvd,
    u16* __restrict__ WtB, u16* __restrict__ WqB,
    u16* __restrict__ WksB, u16* __restrict__ WkdB,
    u16* __restrict__ WvsB, u16* __restrict__ WvdB,
    const int* __restrict__ ei, const float* __restrict__ esame,
    int* __restrict__ cnt, int E)
{
    if (blockIdx.x < 12) {
        int task = blockIdx.x * 4 + (threadIdx.x >> 6);  // 0..47
        int lane = threadIdx.x & 63;
        int wsel = task >> 3, f = task & 7;
        int c = lane & 15, quad = lane >> 4;
        int nt = f >> 1, kk = f & 1;
        for (int j = 0; j < 8; ++j) {
            int n = nt * 16 + c, k = kk * 32 + quad * 8 + j;
            float v; u16* dp; bool h16 = false;
            switch (wsel) {
                case 0: v = Wt[n * 65 + k];  dp = WtB;  break;
                case 1: v = Wq[n * 64 + k];  dp = WqB;  break;
                case 2: v = Wks[k * 64 + n]; dp = WksB; break;
                case 3: v = Wkd[k * 64 + n]; dp = WkdB; break;
                case 4: v = Wvs[n * 64 + pi_perm(k)]; dp = WvsB; h16 = true; break;
                default: v = Wvd[n * 64 + pi_perm(k)]; dp = WvdB; h16 = true; break;
            }
            dp[(f * 64 + lane) * 8 + j] = h16 ? f2h(v) : f2bf(v);
        }
    } else {
        int gid = (blockIdx.x - 12) * 256 + threadIdx.x;
        int stride = (gridDim.x - 12) * 256;
        for (int e = gid; e < E; e += stride) {
            int key = 2 * ei[E + e] + (esame[e] > 0.5f ? 0 : 1);
            atomicAdd(&cnt[key], 1);
        }
    }
}

// ---- hierarchical scan: A) per-block reduce, B) scan block sums, C) local scan + offset
#define SCAN_CHUNK 2048

__global__ __launch_bounds__(256) void scan_phaseA(const int* __restrict__ cnt,
                                                   int* __restrict__ bsum, int M)
{
    int base = blockIdx.x * SCAN_CHUNK;
    int s = 0;
    for (int i = threadIdx.x; i < SCAN_CHUNK; i += 256) {
        int idx = base + i;
        s += (idx < M) ? cnt[idx] : 0;
    }
    #pragma unroll
    for (int o = 32; o; o >>= 1) s += __shfl_xor(s, o);
    __shared__ int red[4];
    if ((threadIdx.x & 63) == 0) red[threadIdx.x >> 6] = s;
    __syncthreads();
    if (threadIdx.x == 0) bsum[blockIdx.x] = red[0] + red[1] + red[2] + red[3];
}

__global__ __launch_bounds__(256) void scan_phaseB(int* __restrict__ bsum, int nb)
{
    __shared__ int tmp[256];
    int v = (threadIdx.x < nb) ? bsum[threadIdx.x] : 0;
    tmp[threadIdx.x] = v;
    __syncthreads();
    if (threadIdx.x == 0) {
        int acc = 0;
        for (int i = 0; i < nb; ++i) { int t = tmp[i]; tmp[i] = acc; acc += t; }
    }
    __syncthreads();
    if (threadIdx.x < nb) bsum[threadIdx.x] = tmp[threadIdx.x];
}

__global__ __launch_bounds__(256) void scan_phaseC(const int* __restrict__ cnt,
                                                   const int* __restrict__ bsum,
                                                   int* __restrict__ cursor, int M)
{
    int base = blockIdx.x * SCAN_CHUNK;
    int i0 = base + threadIdx.x * 8;
    int vals[8];
    int tsum = 0;
    #pragma unroll
    for (int j = 0; j < 8; ++j) {
        int idx = i0 + j;
        vals[j] = (idx < M) ? cnt[idx] : 0;
        tsum += vals[j];
    }
    int lane = threadIdx.x & 63;
    int w = threadIdx.x >> 6;
    int inc = tsum;
    #pragma unroll
    for (int o = 1; o < 64; o <<= 1) {
        int v = __shfl_up(inc, o);
        if (lane >= o) inc += v;
    }
    __shared__ int wsum[4];
    if (lane == 63) wsum[w] = inc;
    __syncthreads();
    int woff = 0;
    #pragma unroll
    for (int k = 0; k < 4; ++k) woff += (k < w) ? wsum[k] : 0;
    int excl = woff + (inc - tsum) + bsum[blockIdx.x];
    #pragma unroll
    for (int j = 0; j < 8; ++j) {
        int idx = i0 + j;
        if (idx < M) cursor[idx] = excl;
        excl += vals[j];
    }
}

// ---- K3 (fat): blocks [0,GS) counting-sort scatter (1 edge/thread) |
//                blocks [GS,GS+GQ) fused LN + q-chain (independent of sort)
__global__ __launch_bounds__(256) void scatter_qgemm(
    const int* __restrict__ ei, const float* __restrict__ et,
    const float* __restrict__ esame, int* __restrict__ cursor,
    int2* __restrict__ ev, int* __restrict__ keyv, int E, int GS,
    const float* __restrict__ x, const float* __restrict__ gamma, const float* __restrict__ beta,
    const u16* __restrict__ WqB, const u16* __restrict__ WksB, const u16* __restrict__ WkdB,
    const float* __restrict__ bq, const float* __restrict__ bks, const float* __restrict__ bkd,
    u16* __restrict__ xnb, u16* __restrict__ qk2, float* __restrict__ bq2, int N)
{
    __shared__ u16 qtile[4][16 * 64];
    __shared__ u16 stile[4][32 * 64];

    if (blockIdx.x < GS) {
        // ---------- scatter: one edge per thread ----------
        int e = blockIdx.x * 256 + threadIdx.x;
        if (e < E) {
            int key = 2 * ei[E + e] + (esame[e] > 0.5f ? 0 : 1);
            int pos = atomicAdd(&cursor[key], 1);
            ev[pos] = make_int2(ei[e], __float_as_int(et[e]));
            keyv[pos] = key;
        }
        return;
    }

    // ---------- qgemm ----------
    const int lane = threadIdx.x & 63;
    const int c = lane & 15, quad = lane >> 4;
    const int w = threadIdx.x >> 6;
    const int wave = (blockIdx.x - GS) * 4 + w;
    const int n0r = wave * 16;
    const bool active = n0r < N;
    const int n0 = active ? n0r : 0;
    const int rowA = (n0 + c < N) ? n0 + c : N - 1;

    // fused LayerNorm in A-fragment layout
    const float* xrow = x + (long)rowA * D;
    f32x4 xa = *(const f32x4*)(xrow + quad * 8);
    f32x4 xb = *(const f32x4*)(xrow + quad * 8 + 4);
    f32x4 xc = *(const f32x4*)(xrow + 32 + quad * 8);
    f32x4 xd = *(const f32x4*)(xrow + 32 + quad * 8 + 4);
    float s = 0.f, s2 = 0.f;
    #pragma unroll
    for (int j = 0; j < 4; ++j) {
        s += xa[j] + xb[j] + xc[j] + xd[j];
        s2 += xa[j] * xa[j] + xb[j] * xb[j] + xc[j] * xc[j] + xd[j] * xd[j];
    }
    s += __shfl_xor(s, 16);  s += __shfl_xor(s, 32);
    s2 += __shfl_xor(s2, 16); s2 += __shfl_xor(s2, 32);
    float mu = s * (1.0f / 64.0f);
    float var = s2 * (1.0f / 64.0f) - mu * mu;
    float rinv = rsqrtf(var + 1e-5f);
    f32x4 ga = *(const f32x4*)(gamma + quad * 8);
    f32x4 gb = *(const f32x4*)(gamma + quad * 8 + 4);
    f32x4 gc = *(const f32x4*)(gamma + 32 + quad * 8);
    f32x4 gd = *(const f32x4*)(gamma + 32 + quad * 8 + 4);
    f32x4 ba = *(const f32x4*)(beta + quad * 8);
    f32x4 bb = *(const f32x4*)(beta + quad * 8 + 4);
    f32x4 bc = *(const f32x4*)(beta + 32 + quad * 8);
    f32x4 bd = *(const f32x4*)(beta + 32 + quad * 8 + 4);
    bf16x8 a0, a1;
    #pragma unroll
    for (int j = 0; j < 4; ++j) {
        a0[j]     = (short)f2bf(fmaf((xa[j] - mu) * rinv, ga[j], ba[j]));
        a0[4 + j] = (short)f2bf(fmaf((xb[j] - mu) * rinv, gb[j], bb[j]));
        a1[j]     = (short)f2bf(fmaf((xc[j] - mu) * rinv, gc[j], bc[j]));
        a1[4 + j] = (short)f2bf(fmaf((xd[j] - mu) * rinv, gd[j], bd[j]));
    }
    *(bf16x8*)(xnb + (long)rowA * D + quad * 8) = a0;
    *(bf16x8*)(xnb + (long)rowA * D + 32 + quad * 8) = a1;

    float bqc[4], bksc[4], bkdc[4];
    #pragma unroll
    for (int t = 0; t < 4; ++t) {
        bqc[t] = bq[t * 16 + c]; bksc[t] = bks[t * 16 + c]; bkdc[t] = bkd[t * 16 + c];
    }

    // GEMM1: q
    f32x4 accq[4];
    #pragma unroll
    for (int t = 0; t < 4; ++t) {
        bf16x8 b0 = *(const bf16x8*)(WqB + ((t * 2 + 0) * 64 + lane) * 8);
        bf16x8 b1 = *(const bf16x8*)(WqB + ((t * 2 + 1) * 64 + lane) * 8);
        f32x4 z = {0.f, 0.f, 0.f, 0.f};
        z = __builtin_amdgcn_mfma_f32_16x16x32_bf16(a0, b0, z, 0, 0, 0);
        z = __builtin_amdgcn_mfma_f32_16x16x32_bf16(a1, b1, z, 0, 0, 0);
        accq[t] = z;
    }
    #pragma unroll
    for (int r = 0; r < 4; ++r) {
        float qv[4], ss = 0.f, sd = 0.f;
        #pragma unroll
        for (int t = 0; t < 4; ++t) {
            qv[t] = accq[t][r] + bqc[t];
            ss = fmaf(qv[t], bksc[t], ss);
            sd = fmaf(qv[t], bkdc[t], sd);
        }
        #pragma unroll
        for (int o = 1; o < 16; o <<= 1) { ss += __shfl_xor(ss, o); sd += __shfl_xor(sd, o); }
        int nrow = n0 + quad * 4 + r;
        if (active && c == 0 && nrow < N)
            *(float2*)(bq2 + 2 * nrow) = make_float2(ss, sd);
        #pragma unroll
        for (int t = 0; t < 4; ++t)
            qtile[w][(quad * 4 + r) * 64 + t * 16 + c] = f2bf(qv[t]);
    }
    __syncthreads();

    // GEMM2: qks/qkd -> stile rows (2m, 2m+1), pi-permuted positions
    const u16* qrow = &qtile[w][c * 64 + quad * 8];
    bf16x8 q0 = *(const bf16x8*)(qrow);
    bf16x8 q1 = *(const bf16x8*)(qrow + 32);
    #pragma unroll
    for (int t = 0; t < 4; ++t) {
        bf16x8 bs0 = *(const bf16x8*)(WksB + ((t * 2 + 0) * 64 + lane) * 8);
        bf16x8 bs1 = *(const bf16x8*)(WksB + ((t * 2 + 1) * 64 + lane) * 8);
        bf16x8 bd0 = *(const bf16x8*)(WkdB + ((t * 2 + 0) * 64 + lane) * 8);
        bf16x8 bd1 = *(const bf16x8*)(WkdB + ((t * 2 + 1) * 64 + lane) * 8);
        f32x4 zs = {0.f, 0.f, 0.f, 0.f}, zd = {0.f, 0.f, 0.f, 0.f};
        zs = __builtin_amdgcn_mfma_f32_16x16x32_bf16(q0, bs0, zs, 0, 0, 0);
        zs = __builtin_amdgcn_mfma_f32_16x16x32_bf16(q1, bs1, zs, 0, 0, 0);
        zd = __builtin_amdgcn_mfma_f32_16x16x32_bf16(q0, bd0, zd, 0, 0, 0);
        zd = __builtin_amdgcn_mfma_f32_16x16x32_bf16(q1, bd1, zd, 0, 0, 0);
        #pragma unroll
        for (int r = 0; r < 4; ++r) {
            int m = quad * 4 + r;
            stile[w][(2 * m + 0) * 64 + c * 4 + t] = f2bf(zs[r]);
            stile[w][(2 * m + 1) * 64 + c * 4 + t] = f2bf(zd[r]);
        }
    }
    __syncthreads();
    if (active) {
        int nrows = min(16, N - n0);
        const u16x8* sp = (const u16x8*)&stile[w][0];
        u16x8* dp = (u16x8*)(qk2 + (long)(2 * n0) * D);
        int cnt8 = nrows * 16;
        for (int j = lane; j < cnt8; j += 64) dp[j] = sp[j];
    }
}

// ---- K4: edge pass over key-sorted edges (run-aggregation in registers)
__global__ __launch_bounds__(256) void edge_pass(
    const int2* __restrict__ ev, const int* __restrict__ keyv,
    const u16* __restrict__ xnb, const u16* __restrict__ WtB,
    const float* __restrict__ Wt, const float* __restrict__ bt,
    const u16* __restrict__ qk2, const float* __restrict__ bq2,
    u16* __restrict__ A, float* __restrict__ den, int E, int chunk)
{
    const int lane = threadIdx.x & 63;
    const int c = lane & 15, quad = lane >> 4;
    const int wave = blockIdx.x * 4 + (threadIdx.x >> 6);
    const long base = (long)wave * chunk;
    if (base >= E) return;
    const long end = (base + chunk < (long)E) ? base + chunk : (long)E;
    const int qchunk = chunk >> 2;

    bf16x8 bfrag[8];
    #pragma unroll
    for (int f = 0; f < 8; ++f)
        bfrag[f] = *(const bf16x8*)(WtB + (f * 64 + lane) * 8);

    float btc[4], w64c[4], dva[4];
    #pragma unroll
    for (int t = 0; t < 4; ++t) {
        int dim = t * 16 + c;
        btc[t] = bt[dim];
        w64c[t] = Wt[dim * 65 + 64];
        dva[t] = 200.0f * expf(-9.210340371976184f * (float)(2 * (dim >> 1)) * (1.0f / 64.0f));
    }
    const float phoff = (c & 1) ? 1.5707963267948966f : 0.0f;

    int cur_key = -1;
    float racc0 = 0.f, racc1 = 0.f, racc2 = 0.f, racc3 = 0.f, rden = 0.f;
    ushort4 q4 = {0, 0, 0, 0};
    float bqv = 0.f;

    const long rowbase = base + (long)(c >> 2) * qchunk + (c & 3);

    for (int i = 0; i < qchunk; i += 4) {
        long eidx = rowbase + i;
        long ec = eidx < end ? eidx : end - 1;
        int2 evv = ev[ec];
        int keyL = keyv[ec];
        int srcL = evv.x;
        float tL = __int_as_float(evv.y);

        const u16* ar = xnb + (long)srcL * D + quad * 8;
        bf16x8 a0 = *(const bf16x8*)(ar);
        bf16x8 a1 = *(const bf16x8*)(ar + 32);

        f32x4 acc[4];
        #pragma unroll
        for (int t = 0; t < 4; ++t) {
            f32x4 z = {0.f, 0.f, 0.f, 0.f};
            z = __builtin_amdgcn_mfma_f32_16x16x32_bf16(a0, bfrag[t * 2 + 0], z, 0, 0, 0);
            z = __builtin_amdgcn_mfma_f32_16x16x32_bf16(a1, bfrag[t * 2 + 1], z, 0, 0, 0);
            acc[t] = z;
        }

        #pragma unroll
        for (int r = 0; r < 4; ++r) {
            int m = quad * 4 + r;
            int keym = __shfl(keyL, m);
            float tm = __shfl(tL, m);
            long eglob = base + (long)quad * qchunk + i + r;
            bool vm = eglob < end;

            float xtv[4];
            #pragma unroll
            for (int t = 0; t < 4; ++t) {
                float v = gelu_tanh(acc[t][r] + fmaf(tm, w64c[t], btc[t]));
                v += __sinf(fmaf(tm, dva[t], phoff));
                xtv[t] = v;
            }

            if (keym != cur_key) {
                if (cur_key >= 0) {
                    u16* ap = A + (long)cur_key * D + c * 4;
                    atomic_pk_add_f16(ap, racc0, racc1);
                    atomic_pk_add_f16(ap + 2, racc2, racc3);
                    if (c == 0) atomicAdd(&den[cur_key], rden);
                }
                cur_key = keym;
                q4 = *(const ushort4*)(qk2 + (long)keym * D + c * 4);
                bqv = bq2[keym];
                racc0 = racc1 = racc2 = racc3 = 0.f;
                rden = 0.f;
            }

            float p = xtv[0] * bf2f(q4.x);
            p = fmaf(xtv[1], bf2f(q4.y), p);
            p = fmaf(xtv[2], bf2f(q4.z), p);
            p = fmaf(xtv[3], bf2f(q4.w), p);
            #pragma unroll
            for (int o = 1; o < 16; o <<= 1) p += __shfl_xor(p, o);
            float ex = vm ? __expf((p + bqv) * 0.125f) : 0.0f;

            racc0 = fmaf(ex, xtv[0], racc0);
            racc1 = fmaf(ex, xtv[1], racc1);
            racc2 = fmaf(ex, xtv[2], racc2);
            racc3 = fmaf(ex, xtv[3], racc3);
            if (c == 0) rden += ex;
        }
    }

    if (cur_key >= 0) {
        u16* ap = A + (long)cur_key * D + c * 4;
        atomic_pk_add_f16(ap, racc0, racc1);
        atomic_pk_add_f16(ap + 2, racc2, racc3);
        if (c == 0) atomicAdd(&den[cur_key], rden);
    }
}

// ---- K5: node post (MFMA value-GEMM + output)
__global__ __launch_bounds__(256) void vgemm(
    const float* __restrict__ x, const u16* __restrict__ A, const float* __restrict__ den,
    const u16* __restrict__ WvsB, const u16* __restrict__ WvdB,
    const float* __restrict__ bvs, const float* __restrict__ bvd,
    float* __restrict__ out, int N)
{
    const int lane = threadIdx.x & 63;
    const int c = lane & 15, quad = lane >> 4;
    const int wave = blockIdx.x * 4 + (threadIdx.x >> 6);
    const int n0 = wave * 16;
    if (n0 >= N) return;
    const int rowA = (n0 + c < N) ? n0 + c : N - 1;

    float bvsc[4], bvdc[4];
    #pragma unroll
    for (int t = 0; t < 4; ++t) { bvsc[t] = bvs[t * 16 + c]; bvdc[t] = bvd[t * 16 + c]; }

    const u16* srow = A + (long)(2 * rowA) * D + quad * 8;
    const u16* drow = A + (long)(2 * rowA + 1) * D + quad * 8;
    f16x8 s0 = *(const f16x8*)(srow);
    f16x8 s1 = *(const f16x8*)(srow + 32);
    f16x8 d0 = *(const f16x8*)(drow);
    f16x8 d1 = *(const f16x8*)(drow + 32);

    f32x4 oacc[4];
    #pragma unroll
    for (int t = 0; t < 4; ++t) {
        f16x8 bs0 = *(const f16x8*)(WvsB + ((t * 2 + 0) * 64 + lane) * 8);
        f16x8 bs1 = *(const f16x8*)(WvsB + ((t * 2 + 1) * 64 + lane) * 8);
        f16x8 bd0 = *(const f16x8*)(WvdB + ((t * 2 + 0) * 64 + lane) * 8);
        f16x8 bd1 = *(const f16x8*)(WvdB + ((t * 2 + 1) * 64 + lane) * 8);
        f32x4 z = {0.f, 0.f, 0.f, 0.f};
        z = __builtin_amdgcn_mfma_f32_16x16x32_f16(s0, bs0, z, 0, 0, 0);
        z = __builtin_amdgcn_mfma_f32_16x16x32_f16(s1, bs1, z, 0, 0, 0);
        z = __builtin_amdgcn_mfma_f32_16x16x32_f16(d0, bd0, z, 0, 0, 0);
        z = __builtin_amdgcn_mfma_f32_16x16x32_f16(d1, bd1, z, 0, 0, 0);
        oacc[t] = z;
    }

    #pragma unroll
    for (int r = 0; r < 4; ++r) {
        int n = n0 + quad * 4 + r;
        if (n >= N) continue;
        float ds = den[2 * n], dd = den[2 * n + 1];
        float inv = 1.0f / (ds + dd + 1e-16f);
        float fs = ds * inv, fd = dd * inv;
        #pragma unroll
        for (int t = 0; t < 4; ++t) {
            long idx = (long)n * D + t * 16 + c;
            float o = fmaf(oacc[t][r], inv, fmaf(fs, bvsc[t], fd * bvdc[t]));
            out[idx] = x[idx] + gelu_erf(o);
        }
    }
}

extern "C" void kernel_launch(void* const* d_in, const int* in_sizes, int n_in,
                              void* d_out, int out_size, void* d_ws, size_t ws_size,
                              hipStream_t stream) {
    const float* x        = (const float*)d_in[0];
    const int*   ei       = (const int*)d_in[1];
    const float* et       = (const float*)d_in[2];
    const float* esame    = (const float*)d_in[4];
    const float* ln_gamma = (const float*)d_in[5];
    const float* ln_beta  = (const float*)d_in[6];
    const float* Wt  = (const float*)d_in[7];
    const float* bt  = (const float*)d_in[8];
    const float* Wq  = (const float*)d_in[9];
    const float* bq  = (const float*)d_in[10];
    const float* Wks = (const float*)d_in[11];
    const float* bks = (const float*)d_in[12];
    const float* Wkd = (const float*)d_in[13];
    const float* bkd = (const float*)d_in[14];
    const float* Wvs = (const float*)d_in[15];
    const float* bvs = (const float*)d_in[16];
    const float* Wvd = (const float*)d_in[17];
    const float* bvd = (const float*)d_in[18];
    float* out = (float*)d_out;

    const int N = in_sizes[0] / D;   // 50000
    const int E = in_sizes[2];       // 800000
    const int M = 2 * N;             // key space

    u16* A      = (u16*)d_ws;
    float* den  = (float*)(A + (long)M * D);
    int* cnt    = (int*)(den + M);
    int* cursor = cnt + M;
    float* bq2  = (float*)(cursor + M);
    int2* ev    = (int2*)(bq2 + M);
    int* keyv   = (int*)(ev + E);
    int* bsum   = keyv + E;                      // scan block sums (<=256)
    u16* xnb    = (u16*)(bsum + 256);
    u16* qk2    = xnb + (long)N * D;
    u16* WtB    = qk2 + (long)M * D;
    u16* WqB    = WtB + 4096;
    u16* WksB   = WqB + 4096;
    u16* WkdB   = WksB + 4096;
    u16* WvsB   = WkdB + 4096;
    u16* WvdB   = WvsB + 4096;

    // zero A + den + cnt in one shot (contiguous)
    hipMemsetAsync(A, 0, (size_t)M * D * 2 + (size_t)M * 4 * 2, stream);

    prep_hist<<<12 + 976, 256, 0, stream>>>(Wt, Wq, Wks, Wkd, Wvs, Wvd,
                                            WtB, WqB, WksB, WkdB, WvsB, WvdB,
                                            ei, esame, cnt, E);
    const int nbScan = (M + SCAN_CHUNK - 1) / SCAN_CHUNK;   // 49 @ M=100k
    scan_phaseA<<<nbScan, 256, 0, stream>>>(cnt, bsum, M);
    scan_phaseB<<<1, 256, 0, stream>>>(bsum, nbScan);
    scan_phaseC<<<nbScan, 256, 0, stream>>>(cnt, bsum, cursor, M);

    const int GS = (E + 255) / 256;              // scatter blocks (3125)
    const int GQ = ((N + 15) / 16 + 3) / 4;      // qgemm blocks (782)
    scatter_qgemm<<<GS + GQ, 256, 0, stream>>>(
        ei, et, esame, cursor, ev, keyv, E, GS,
        x, ln_gamma, ln_beta, WqB, WksB, WkdB, bq, bks, bkd,
        xnb, qk2, bq2, N);

    const int nwaves = 2048 * 4;
    const int chunk = ((E + nwaves * 16 - 1) / (nwaves * 16)) * 16;  // 112 @ E=800k
    edge_pass<<<2048, 256, 0, stream>>>(ev, keyv, xnb, WtB, Wt, bt,
                                        qk2, bq2, A, den, E, chunk);
    vgemm<<<GQ, 256, 0, stream>>>(x, A, den, WvsB, WvdB, bvs, bvd, out, N);
}